// Round 10
// baseline (72.723 us; speedup 1.0000x reference)
//
#include <hip/hip_runtime.h>
#include <hip/hip_bf16.h>

// FilterBank via bf16 MFMA, swapped operands:
//   D[t_row, band_col] = sum_k A[t,k] B[k,band],  A[i,k] = xpad[t0+i+k+2],
//   B[k,n] = W[n,k]  (xpad[i] = x[i-64], zero outside [0,1000))
// C/D layout: col = lane&15 = band n, row = 4*(lane>>4)+reg = t -> lane's 4
// acc regs are 4 CONSECUTIVE t of one band.
// Round 10: grid-strided row loop for DENSE WRITE FRONT — 1024 blocks x 4
// rows (bc = 1024*it + bid): resident cohort always covers a contiguous
// ~37MB output slice sweeping linearly (fill-kernel pattern), instead of
// 4096 blocks scattering over all 147MB at once. Flush: 2 half-row rounds
// through stg (aliases dead xs LDS), each wave stores long contiguous 1KB
// runs covering 2-3 whole band rows.

#define T_LEN      1000
#define NB         9
#define KP         128
#define S_COPY     1160      // shorts per shifted copy
#define SLOTS      145       // 16B slots per copy
#define STG_STRIDE 520       // floats per band row in stg (520%32==8)
#define SMEM_BYTES (NB * STG_STRIDE * 4)   // 18720 >= 8*S_COPY*2 = 18560

typedef __attribute__((ext_vector_type(8))) short short8;
typedef __attribute__((ext_vector_type(4))) float f32x4;

__device__ __forceinline__ unsigned int f2bf(float f) {
    union { __hip_bfloat16 h; unsigned short u; } cv;
    cv.h = __float2bfloat16(f);
    return (unsigned int)cv.u;
}

__global__ __launch_bounds__(256) void prep_taps(const float* __restrict__ kern,
                                                 unsigned short* __restrict__ kwb) {
    const int t = threadIdx.x;
    #pragma unroll
    for (int i = 0; i < 8; ++i) {
        int idx = t + 256 * i;            // 0..2047 over [16][128]
        int band = idx >> 7, k = idx & 127;
        float v = (band < NB && k < 125) ? kern[band * 125 + k] : 0.f;
        kwb[idx] = (unsigned short)f2bf(v);
    }
}

__global__ __launch_bounds__(256) void fbank_mfma(
    const float* __restrict__ x,
    const unsigned short* __restrict__ kwb,
    float* __restrict__ out)
{
    __shared__ char smem[SMEM_BYTES];            // xs (compute) / stg (flush) alias
    unsigned short* xs = reinterpret_cast<unsigned short*>(smem);
    float* stg = reinterpret_cast<float*>(smem);

    const int tid  = threadIdx.x;
    const int bid  = blockIdx.x;
    const int lane = tid & 63;
    const int wid  = tid >> 6;
    const int n = lane & 15, g = lane >> 4;      // n = band col, g = k/row group

    // ---- B frags (taps): clean aligned short8 loads from prepped kwb ----
    short8 bt[4];
    #pragma unroll
    for (int kk = 0; kk < 4; ++kk)
        bt[kk] = *reinterpret_cast<const short8*>(kwb + n * KP + kk * 32 + g * 8);

    const int t0w = wid << 8;                    // wave owns t in [256w, 256w+256)
    const int rl  = (n + 2) & 7;                 // A-row i = n : alignment class
    const char* xsb = reinterpret_cast<const char*>(xs);
    // F[u] element index s = t0w + 2 + n + 8g + 16u, LDS elem = 1159*rl + s
    const int LB = 2 * (1159 * rl + 2 + n + 8 * g + t0w);

    for (int it = 0; it < 4; ++it) {
        const int bc = (it << 10) + bid;         // contiguous 1024-row window
        const int b  = bc >> 6, c = bc & 63;
        const float* xrow = x + (size_t)bc * T_LEN;

        __syncthreads();                         // smem free from prev iteration

        // ---- stage 8 shifted bf16 copies: copy r, slot q = xpad[8q+r..+7] ----
        {
            const int r = tid >> 5, q0 = tid & 31;
            #pragma unroll
            for (int i = 0; i < 5; ++i) {
                int q = q0 + 32 * i;
                if (q < SLOTS) {
                    int idx0 = 8 * q + r - 64;   // x-index of element 0
                    unsigned int d[4];
                    #pragma unroll
                    for (int e2 = 0; e2 < 4; ++e2) {
                        int i0 = idx0 + 2 * e2, i1 = i0 + 1;
                        float v0 = ((unsigned)i0 < T_LEN) ? xrow[i0] : 0.f;
                        float v1 = ((unsigned)i1 < T_LEN) ? xrow[i1] : 0.f;
                        d[e2] = f2bf(v0) | (f2bf(v1) << 16);
                    }
                    *reinterpret_cast<uint4*>(&xs[r * S_COPY + 8 * q]) =
                        make_uint4(d[0], d[1], d[2], d[3]);
                }
            }
        }
        __syncthreads();

        // ---- compute: 16 persistent acc chains ----
        f32x4 acc[16];
        short8 F[8];
        #pragma unroll
        for (int u = 0; u < 6; ++u)
            F[u] = *reinterpret_cast<const short8*>(xsb + LB + 32 * u);
        #pragma unroll
        for (int m = 0; m < 16; ++m) {
            F[(m + 6) & 7] = *reinterpret_cast<const short8*>(xsb + LB + 32 * (m + 6));
            f32x4 a = {0.f, 0.f, 0.f, 0.f};
            #pragma unroll
            for (int kk = 0; kk < 4; ++kk)
                a = __builtin_amdgcn_mfma_f32_16x16x32_bf16(F[(m + 2 * kk) & 7], bt[kk], a, 0, 0, 0);
            acc[m] = a;
        }

        __syncthreads();                         // all xs reads done; xs dead

        // ---- flush: two half-row rounds through stg ----
        #pragma unroll
        for (int h = 0; h < 2; ++h) {
            // waves holding this t-half dump acc into stg[band][t - 512h]
            if ((wid >> 1) == h && n < NB) {
                const int toff = (wid & 1) << 8;
                #pragma unroll
                for (int m = 0; m < 16; ++m)
                    *reinterpret_cast<f32x4*>(stg + n * STG_STRIDE + toff + 16 * m + 4 * g) = acc[m];
            }
            __syncthreads();
            // stores: 18 wave-instrs (9 bands x 2), wave w takes a contiguous
            // run of 5 (wave 3: 3) -> long per-wave streams, 1KB/instr
            const int q0 = wid * 5;
            const int qe = (wid == 3) ? 18 : q0 + 5;
            for (int q = q0; q < qe; ++q) {
                const int band = q >> 1, part = q & 1;
                const int tloc = (h << 9) + (part << 8) + (lane << 2);
                if (tloc + 4 <= T_LEN) {
                    f32x4 v = *reinterpret_cast<const f32x4*>(
                        stg + band * STG_STRIDE + (part << 8) + (lane << 2));
                    *reinterpret_cast<f32x4*>(
                        out + ((size_t)(b * NB + band) * 64 + c) * T_LEN + tloc) = v;
                }
            }
            if (h == 0) __syncthreads();         // before waves 2,3 overwrite stg
        }
    }
}

extern "C" void kernel_launch(void* const* d_in, const int* in_sizes, int n_in,
                              void* d_out, int out_size, void* d_ws, size_t ws_size,
                              hipStream_t stream) {
    const float* x    = (const float*)d_in[0];
    const float* kern = (const float*)d_in[1];
    float* out = (float*)d_out;
    unsigned short* kwb = (unsigned short*)d_ws;   // (16,128) bf16 padded taps

    prep_taps<<<1, 256, 0, stream>>>(kern, kwb);
    fbank_mfma<<<1024, 256, 0, stream>>>(x, kwb, out);
}

// Round 11
// 56.864 us; speedup vs baseline: 1.2789x; 1.2789x over previous
//
#include <hip/hip_runtime.h>
#include <hip/hip_bf16.h>

// FilterBank via bf16 MFMA, swapped operands:
//   D[t_row, band_col] = sum_k A[t,k] B[k,band],  A[i,k] = xpad[t0+i+k+2],
//   B[k,n] = W[n,k]  (xpad[i] = x[i-64], zero outside [0,1000))
// C/D layout: col = lane&15 = band n, row = 4*(lane>>4)+reg = t -> lane's 4
// acc regs are 4 CONSECUTIVE t of one band.
// Round 11 composite of proven-best pieces:
//  - taps staged to LDS IN-KERNEL (8 guarded loads + 1 ds_write_b128/thread,
//    [16][136] stride -> 2-way-free frag reads) — kills both the fused-taps
//    32-load prologue (r6/r8, +6-8us) AND the serial prep launch (r9).
//  - 8-shifted-copy x staging (verified r3-r10).
//  - persistent 16-chain MFMA compute (r8-r10, max ILP, 72 VGPR).
//  - direct stores (r6): store shape proven irrelevant (r3/r4, r6/r7/r8
//    all ~null) -> cheapest epilogue, no extra barriers.
//  - bijective XCD swizzle (r9): contiguous 18MB out region per XCD.
//  - single kernel launch, LDS 22.9KB -> 7 blocks/CU.

#define T_LEN    1000
#define NB       9
#define S_COPY   1160      // shorts per shifted copy
#define SLOTS    145       // 16B slots per copy
#define WT_STRIDE 136      // shorts per tap row (272B: 2-way bank aliasing = free)

typedef __attribute__((ext_vector_type(8))) short short8;
typedef __attribute__((ext_vector_type(4))) float f32x4;

__device__ __forceinline__ unsigned int f2bf(float f) {
    union { __hip_bfloat16 h; unsigned short u; } cv;
    cv.h = __float2bfloat16(f);
    return (unsigned int)cv.u;
}

__global__ __launch_bounds__(256) void fbank_mfma(
    const float* __restrict__ x,
    const float* __restrict__ kern,
    float* __restrict__ out)
{
    __shared__ unsigned short xs[8 * S_COPY];       // 18560 B
    __shared__ unsigned short wt[16 * WT_STRIDE];   // 4352 B

    const int tid = threadIdx.x;
    const int bid = blockIdx.x;
    // XCD swizzle: contiguous 512-row chunk per XCD (4096 % 8 == 0, bijective)
    const int bc  = ((bid & 7) << 9) + (bid >> 3);
    const int b   = bc >> 6, c = bc & 63;
    const float* xrow = x + (size_t)bc * T_LEN;

    // ---- stage taps into LDS: thread t -> [band = t>>4][k = (t&15)*8 .. +7] ----
    {
        const int band = tid >> 4, k0 = (tid & 15) << 3;
        unsigned int d[4];
        #pragma unroll
        for (int e2 = 0; e2 < 4; ++e2) {
            int k = k0 + 2 * e2;
            float v0 = (band < NB && k < 125)     ? kern[band * 125 + k]     : 0.f;
            float v1 = (band < NB && k + 1 < 125) ? kern[band * 125 + k + 1] : 0.f;
            d[e2] = f2bf(v0) | (f2bf(v1) << 16);
        }
        *reinterpret_cast<uint4*>(&wt[band * WT_STRIDE + k0]) =
            make_uint4(d[0], d[1], d[2], d[3]);
    }

    // ---- stage 8 shifted bf16 copies: copy r, slot q = xpad[8q+r .. +7] ----
    {
        const int r = tid >> 5, q0 = tid & 31;
        #pragma unroll
        for (int i = 0; i < 5; ++i) {
            int q = q0 + 32 * i;
            if (q < SLOTS) {
                int idx0 = 8 * q + r - 64;       // x-index of element 0
                unsigned int d[4];
                #pragma unroll
                for (int e2 = 0; e2 < 4; ++e2) {
                    int i0 = idx0 + 2 * e2, i1 = i0 + 1;
                    float v0 = ((unsigned)i0 < T_LEN) ? xrow[i0] : 0.f;
                    float v1 = ((unsigned)i1 < T_LEN) ? xrow[i1] : 0.f;
                    d[e2] = f2bf(v0) | (f2bf(v1) << 16);
                }
                *reinterpret_cast<uint4*>(&xs[r * S_COPY + 8 * q]) =
                    make_uint4(d[0], d[1], d[2], d[3]);
            }
        }
    }

    const int lane = tid & 63;
    const int wid  = tid >> 6;
    const int n = lane & 15, g = lane >> 4;      // n = band col, g = k/row group

    __syncthreads();

    // ---- B frags (taps) from LDS: 16B-aligned, 2-way-free ----
    short8 bt[4];
    #pragma unroll
    for (int kk = 0; kk < 4; ++kk)
        bt[kk] = *reinterpret_cast<const short8*>(wt + n * WT_STRIDE + kk * 32 + g * 8);

    const int t0w = wid << 8;                    // wave owns t in [256w, 256w+256)
    const int rl  = (n + 2) & 7;                 // A-row i = n : alignment class
    const char* xsb = reinterpret_cast<const char*>(xs);
    // F[u] element index s = t0w + 2 + n + 8g + 16u, LDS elem = 1159*rl + s
    const int LB = 2 * (1159 * rl + 2 + n + 8 * g + t0w);

    short8 F[8];
    #pragma unroll
    for (int u = 0; u < 6; ++u)
        F[u] = *reinterpret_cast<const short8*>(xsb + LB + 32 * u);

    // ---- compute: 16 persistent acc chains ----
    f32x4 acc[16];
    #pragma unroll
    for (int m = 0; m < 16; ++m) {
        F[(m + 6) & 7] = *reinterpret_cast<const short8*>(xsb + LB + 32 * (m + 6));
        f32x4 a = {0.f, 0.f, 0.f, 0.f};
        #pragma unroll
        for (int kk = 0; kk < 4; ++kk)
            a = __builtin_amdgcn_mfma_f32_16x16x32_bf16(F[(m + 2 * kk) & 7], bt[kk], a, 0, 0, 0);
        acc[m] = a;
    }

    // ---- direct stores (shape proven irrelevant; cheapest epilogue) ----
    const bool bandok = (n < NB);
    float* obase = out + ((size_t)(b * NB + n) * 64 + c) * T_LEN + t0w + 4 * g;
    #pragma unroll
    for (int m = 0; m < 16; ++m) {
        const int t4 = t0w + 16 * m + 4 * g;
        if (bandok && t4 + 4 <= T_LEN)
            *reinterpret_cast<f32x4*>(obase + 16 * m) = acc[m];
    }
}

extern "C" void kernel_launch(void* const* d_in, const int* in_sizes, int n_in,
                              void* d_out, int out_size, void* d_ws, size_t ws_size,
                              hipStream_t stream) {
    const float* x    = (const float*)d_in[0];
    const float* kern = (const float*)d_in[1];
    float* out = (float*)d_out;

    fbank_mfma<<<64 * 64, 256, 0, stream>>>(x, kern, out);
}